// Round 5
// baseline (273.220 us; speedup 1.0000x reference)
//
#include <hip/hip_runtime.h>
#include <math.h>

#define B_  32
#define S_  4096
#define E_  256
#define A_  256
#define DE_ 512

typedef __attribute__((ext_vector_type(8))) short short8;
typedef __attribute__((ext_vector_type(4))) float f32x4;

__device__ inline unsigned short f2bf(float x) {
    unsigned int u = __float_as_uint(x);
    u += 0x7FFFu + ((u >> 16) & 1u);      // round-to-nearest-even
    return (unsigned short)(u >> 16);
}
__device__ inline float tanh_fast(float x) {
    x = fminf(fmaxf(x, -15.f), 15.f);
    float t = __expf(2.f * x);
    return (t - 1.f) * __builtin_amdgcn_rcpf(t + 1.f);
}

// ---- Prep: block 0..63 = wprep (pack We hi/lo bf16 in fragment order),
//            block 64..95 = proj, block 96 = zero attended region of out.
__global__ __launch_bounds__(256) void prep_kernel(
    const float* __restrict__ W, const float* __restrict__ dh,
    const float* __restrict__ bias, unsigned short* __restrict__ wepk,
    float* __restrict__ proj, float* __restrict__ out)
{
    __shared__ float dh_lds[E_];
    const int bk  = blockIdx.x;
    const int tid = threadIdx.x;
    if (bk < 64) {
        // unit = c*2048 + plane*1024 + kg*256 + a; 8 bf16 = We[a][c*32+kg*8..+8]
        const int idx = bk * 256 + tid;
        const int c     = idx >> 11;
        const int r     = idx & 2047;
        const int plane = r >> 10;
        const int kg    = (r >> 8) & 3;
        const int a     = r & 255;
        const float* src = W + (size_t)a * DE_ + E_ + c * 32 + kg * 8;
        unsigned int pk[4];
        #pragma unroll
        for (int j = 0; j < 4; ++j) {
            float x0 = src[2 * j], x1 = src[2 * j + 1];
            unsigned int u0 = __float_as_uint(x0) & 0xFFFF0000u;
            unsigned int u1 = __float_as_uint(x1) & 0xFFFF0000u;
            if (plane) {
                unsigned short l0 = f2bf(x0 - __uint_as_float(u0));
                unsigned short l1 = f2bf(x1 - __uint_as_float(u1));
                pk[j] = (unsigned int)l0 | ((unsigned int)l1 << 16);
            } else {
                pk[j] = (u0 >> 16) | u1;
            }
        }
        *(uint4*)&wepk[(size_t)idx * 8] = make_uint4(pk[0], pk[1], pk[2], pk[3]);
    } else if (bk < 96) {
        const int b = bk - 64;
        const int a = tid;
        dh_lds[a] = dh[b * E_ + a];
        __syncthreads();
        float acc = bias[a];
        const float* wrow = W + (size_t)a * DE_;
        #pragma unroll
        for (int d = 0; d < E_; d += 4) {
            float4 w = *(const float4*)(wrow + d);
            acc += dh_lds[d] * w.x + dh_lds[d+1] * w.y
                 + dh_lds[d+2] * w.z + dh_lds[d+3] * w.w;
        }
        proj[b * A_ + a] = acc;
    } else {
        #pragma unroll
        for (int j = tid; j < B_ * E_; j += 256) out[j] = 0.f;
    }
}

// ---- Scores: scores[b][s] = sum_a tanh(proj[b][a] + eo[b,s,:].We[a,:])
//              nsq[b][s]    = ||eo[b,s,:]||^2
// Split-bf16 MFMA, block = 64 s x 256 a, wave = 64 s x 64 a.
// K-loop: ONE barrier/chunk. eo double-buffered in LDS (stride-66 units,
// conflict-free staging writes); We loaded global->VGPR in fragment order
// (no LDS, no global_load_lds, register double-buffer); eo register-prefetch
// one chunk ahead, issued AFTER the barrier so the pre-barrier vmcnt(0)
// never drains a fresh load.
__global__ __launch_bounds__(256, 3) void scores_kernel(
    const float* __restrict__ eo, const unsigned short* __restrict__ wepk,
    const float* __restrict__ proj,
    float* __restrict__ scores, float* __restrict__ nsq)
{
    // eo unit index: buf*528 + plane*264 + kg*66 + row  (1 unit = 16 B)
    __shared__ __align__(16) unsigned short eo_lds[2 * 528 * 8];  // 16896 B
    __shared__ float red4[64 * 65];                                // 16640 B
    __shared__ float npart[512];
    __shared__ float qpart[256];

    const int tid = threadIdx.x;
    const int b   = blockIdx.x & (B_ - 1);
    const int s0  = (blockIdx.x / B_) * 64;
    const int w   = tid >> 6, l = tid & 63;
    const int lq  = l >> 4,  lr = l & 15;

    // eo staging thread map: 8 lanes per row, coalesced float4
    const int erow0 = tid >> 3;          // 0..31 (second row = +32)
    const int ekq   = tid & 7;
    const int ekg   = ekq >> 1, eh = ekq & 1;
    const float* ebase = eo + (size_t)(s0 + erow0) * (B_ * E_) + b * E_ + ekq * 4;

    // B-frag per-lane global base (shorts); instr-constant offsets added per (c,plane,nt)
    const unsigned short* wb = wepk + (size_t)(lq * 256 + w * 64 + lr) * 8;

    f32x4 acc[4][4];
    #pragma unroll
    for (int i = 0; i < 4; ++i)
        #pragma unroll
        for (int j = 0; j < 4; ++j)
            acc[i][j] = (f32x4){0.f, 0.f, 0.f, 0.f};
    float nacc[2] = {0.f, 0.f};

    // prologue: chunk-0 eo + B-frags
    float4 ec0 = *(const float4*)(ebase);
    float4 ec1 = *(const float4*)(ebase + 32 * (B_ * E_));
    short8 bh[4], bl[4], bnh[4], bnl[4];
    #pragma unroll
    for (int nt = 0; nt < 4; ++nt) {
        bh[nt] = *(const short8*)(wb + (size_t)(nt * 16) * 8);
        bl[nt] = *(const short8*)(wb + (size_t)(1024 + nt * 16) * 8);
    }

    #pragma unroll
    for (int c = 0; c < 8; ++c) {
        const int wbuf = (c & 1) * 528;
        // ---- convert + ds_write eo chunk c (conflict-free: bank = 8*ekg+4*row+2*eh)
        #pragma unroll
        for (int it = 0; it < 2; ++it) {
            float4 v = it ? ec1 : ec0;
            nacc[it] += v.x*v.x + v.y*v.y + v.z*v.z + v.w*v.w;
            unsigned int ux = __float_as_uint(v.x) & 0xFFFF0000u;
            unsigned int uy = __float_as_uint(v.y) & 0xFFFF0000u;
            unsigned int uz = __float_as_uint(v.z) & 0xFFFF0000u;
            unsigned int uw = __float_as_uint(v.w) & 0xFFFF0000u;
            unsigned int hp0 = (ux >> 16) | uy;
            unsigned int hp1 = (uz >> 16) | uw;
            unsigned int lp0 = (unsigned int)f2bf(v.x - __uint_as_float(ux))
                             | ((unsigned int)f2bf(v.y - __uint_as_float(uy)) << 16);
            unsigned int lp1 = (unsigned int)f2bf(v.z - __uint_as_float(uz))
                             | ((unsigned int)f2bf(v.w - __uint_as_float(uw)) << 16);
            const int u = wbuf + ekg * 66 + it * 32 + erow0;
            *(uint2*)&eo_lds[(size_t)u * 8 + eh * 4]         = make_uint2(hp0, hp1);
            *(uint2*)&eo_lds[(size_t)(u + 264) * 8 + eh * 4] = make_uint2(lp0, lp1);
        }
        __syncthreads();   // vmcnt ~0 here: all prefetches already consumed
        if (c < 7) {
            // prefetch next chunk AFTER the barrier (stays in flight through MFMAs)
            ec0 = *(const float4*)(ebase + (c + 1) * 32);
            ec1 = *(const float4*)(ebase + 32 * (B_ * E_) + (c + 1) * 32);
            #pragma unroll
            for (int nt = 0; nt < 4; ++nt) {
                bnh[nt] = *(const short8*)(wb + (size_t)((c+1)*2048 + nt*16) * 8);
                bnl[nt] = *(const short8*)(wb + (size_t)((c+1)*2048 + 1024 + nt*16) * 8);
            }
        }
        // ---- compute chunk c
        #pragma unroll
        for (int mt = 0; mt < 4; ++mt) {
            const int au = wbuf + lq * 66 + mt * 16 + lr;
            short8 ah = *(const short8*)&eo_lds[(size_t)au * 8];
            short8 al = *(const short8*)&eo_lds[(size_t)(au + 264) * 8];
            #pragma unroll
            for (int nt = 0; nt < 4; ++nt) {
                acc[mt][nt] = __builtin_amdgcn_mfma_f32_16x16x32_bf16(ah, bh[nt], acc[mt][nt], 0, 0, 0);
                acc[mt][nt] = __builtin_amdgcn_mfma_f32_16x16x32_bf16(ah, bl[nt], acc[mt][nt], 0, 0, 0);
                acc[mt][nt] = __builtin_amdgcn_mfma_f32_16x16x32_bf16(al, bh[nt], acc[mt][nt], 0, 0, 0);
            }
        }
        if (c < 7) {
            #pragma unroll
            for (int nt = 0; nt < 4; ++nt) { bh[nt] = bnh[nt]; bl[nt] = bnl[nt]; }
        }
    }

    // ---- epilogue: tanh + reduce over a (separate LDS arrays, no alias)
    float pr[4];
    #pragma unroll
    for (int nt = 0; nt < 4; ++nt) pr[nt] = proj[b * A_ + w * 64 + nt * 16 + lr];
    #pragma unroll
    for (int mt = 0; mt < 4; ++mt) {
        #pragma unroll
        for (int r = 0; r < 4; ++r) {
            float s = 0.f;
            #pragma unroll
            for (int nt = 0; nt < 4; ++nt)
                s += tanh_fast(pr[nt] + acc[mt][nt][r]);
            // C/D layout: col = lr (a-dim), row = mt*16 + lq*4 + r (s-dim)
            red4[(w * 16 + lr) * 65 + (mt * 16 + lq * 4 + r)] = s;
        }
    }
    npart[tid]       = nacc[0];
    npart[256 + tid] = nacc[1];
    __syncthreads();
    {   // 256-thread reduction: thread (q, r) sums 16 of 64 columns of row r
        const int r = tid & 63, q = tid >> 6;
        float s = 0.f;
        #pragma unroll
        for (int c2 = q * 16; c2 < q * 16 + 16; ++c2) s += red4[c2 * 65 + r];
        qpart[q * 64 + r] = s;
    }
    __syncthreads();
    if (tid < 64) {
        scores[b * S_ + s0 + tid] = qpart[tid] + qpart[64 + tid]
                                  + qpart[128 + tid] + qpart[192 + tid];
        const int base = (tid >> 5) * 256 + (tid & 31) * 8;
        float nq = 0.f;
        #pragma unroll
        for (int q2 = 0; q2 < 8; ++q2) nq += npart[base + q2];
        nsq[b * S_ + s0 + tid] = nq;
    }
}

// ---- Attend (softmax fused): each block recomputes per-b softmax stats from
// L2-hot scores (deterministic, identical across blocks of the same b), then
// computes its 128-row partial of attended + writes attn_map for its rows.
__global__ __launch_bounds__(256) void attend_kernel(
    const float* __restrict__ eo, const float* __restrict__ scores,
    const float* __restrict__ nsq, float* __restrict__ out)
{
    __shared__ float red[256];
    __shared__ float4 acc_red[4][64];
    const int tid = threadIdx.x;
    const int b   = blockIdx.x & (B_ - 1);
    const int ch  = blockIdx.x / B_;

    // softmax stats over full S
    float v[16];
    float m = -1e30f;
    #pragma unroll
    for (int i = 0; i < 16; ++i) {
        v[i] = scores[b * S_ + i * 256 + tid];
        m = fmaxf(m, v[i]);
    }
    red[tid] = m;
    __syncthreads();
    for (int off = 128; off > 0; off >>= 1) {
        if (tid < off) red[tid] = fmaxf(red[tid], red[tid + off]);
        __syncthreads();
    }
    m = red[0];
    __syncthreads();
    float sum = 0.f;
    #pragma unroll
    for (int i = 0; i < 16; ++i) sum += __expf(v[i] - m);
    red[tid] = sum;
    __syncthreads();
    for (int off = 128; off > 0; off >>= 1) {
        if (tid < off) red[tid] += red[tid + off];
        __syncthreads();
    }
    const float inv = 1.f / red[0];

    // attended partial: 4 s-groups x 64 lanes x float4
    const int le = tid & 63, sg = tid >> 6;
    const int s0 = ch * 128 + sg * 32;
    float4 a = make_float4(0.f, 0.f, 0.f, 0.f);
    #pragma unroll 4
    for (int s = 0; s < 32; ++s) {
        float pv = __expf(scores[b * S_ + s0 + s] - m) * inv;
        float4 e = *(const float4*)(eo + (size_t)(s0 + s) * (B_ * E_)
                                       + b * E_ + le * 4);
        a.x = fmaf(pv, e.x, a.x);
        a.y = fmaf(pv, e.y, a.y);
        a.z = fmaf(pv, e.z, a.z);
        a.w = fmaf(pv, e.w, a.w);
    }
    acc_red[sg][le] = a;
    // attn_map for this block's 128 rows
    if (tid < 128) {
        const int s = ch * 128 + tid;
        float pv = __expf(scores[b * S_ + s] - m) * inv;
        out[B_ * E_ + b * S_ + s] = pv * sqrtf(nsq[b * S_ + s]);
    }
    __syncthreads();
    if (tid < 64) {
        float4 a0 = acc_red[0][tid], a1 = acc_red[1][tid];
        float4 a2 = acc_red[2][tid], a3 = acc_red[3][tid];
        float* dst = out + b * E_ + tid * 4;
        atomicAdd(dst + 0, a0.x + a1.x + a2.x + a3.x);
        atomicAdd(dst + 1, a0.y + a1.y + a2.y + a3.y);
        atomicAdd(dst + 2, a0.z + a1.z + a2.z + a3.z);
        atomicAdd(dst + 3, a0.w + a1.w + a2.w + a3.w);
    }
}

extern "C" void kernel_launch(void* const* d_in, const int* in_sizes, int n_in,
                              void* d_out, int out_size, void* d_ws, size_t ws_size,
                              hipStream_t stream)
{
    const float* dh   = (const float*)d_in[0];  // (1,B,D)
    const float* eo   = (const float*)d_in[1];  // (S,B,E)
    const float* W    = (const float*)d_in[2];  // (A, D+E)
    const float* bias = (const float*)d_in[3];  // (A,)
    float* out = (float*)d_out;                 // [attended 8192 | attn_map 131072]
    float* ws  = (float*)d_ws;

    float* projb  = ws;                           // 8192 floats
    float* nsqb   = ws + 8192;                    // 131072 floats
    float* scores = nsqb + S_ * B_;               // 131072 floats
    unsigned short* wepk = (unsigned short*)(scores + S_ * B_);  // 256 KB packed We

    prep_kernel   <<<97,              256, 0, stream>>>(W, dh, bias, wepk, projb, out);
    scores_kernel <<<B_ * (S_ / 64),  256, 0, stream>>>(eo, wepk, projb, scores, nsqb);
    attend_kernel <<<B_ * (S_ / 128), 256, 0, stream>>>(eo, scores, nsqb, out);
}

// Round 6
// 259.357 us; speedup vs baseline: 1.0535x; 1.0535x over previous
//
#include <hip/hip_runtime.h>
#include <math.h>

#define B_  32
#define S_  4096
#define E_  256
#define A_  256
#define DE_ 512

typedef __attribute__((ext_vector_type(8))) short short8;
typedef __attribute__((ext_vector_type(4))) float f32x4;

__device__ inline unsigned short f2bf(float x) {
    unsigned int u = __float_as_uint(x);
    u += 0x7FFFu + ((u >> 16) & 1u);      // round-to-nearest-even
    return (unsigned short)(u >> 16);
}
__device__ inline float tanh_fast(float x) {
    x = fminf(fmaxf(x, -15.f), 15.f);
    float t = __expf(2.f * x);
    return (t - 1.f) * __builtin_amdgcn_rcpf(t + 1.f);
}

// ---- Prep: block 0..63 = pack We hi/lo bf16 (fragment order),
//            block 64..95 = proj, block 96 = zero attended region.
__global__ __launch_bounds__(256) void prep_kernel(
    const float* __restrict__ W, const float* __restrict__ dh,
    const float* __restrict__ bias, unsigned short* __restrict__ wepk,
    float* __restrict__ proj, float* __restrict__ out)
{
    __shared__ float dh_lds[E_];
    const int bk  = blockIdx.x;
    const int tid = threadIdx.x;
    if (bk < 64) {
        // unit = c*2048 + plane*1024 + kg*256 + a; 8 bf16 = We[a][c*32+kg*8..+8]
        const int idx = bk * 256 + tid;
        const int c     = idx >> 11;
        const int r     = idx & 2047;
        const int plane = r >> 10;
        const int kg    = (r >> 8) & 3;
        const int a     = r & 255;
        const float* src = W + (size_t)a * DE_ + E_ + c * 32 + kg * 8;
        unsigned int pk[4];
        #pragma unroll
        for (int j = 0; j < 4; ++j) {
            float x0 = src[2 * j], x1 = src[2 * j + 1];
            unsigned int u0 = __float_as_uint(x0) & 0xFFFF0000u;
            unsigned int u1 = __float_as_uint(x1) & 0xFFFF0000u;
            if (plane) {
                unsigned short l0 = f2bf(x0 - __uint_as_float(u0));
                unsigned short l1 = f2bf(x1 - __uint_as_float(u1));
                pk[j] = (unsigned int)l0 | ((unsigned int)l1 << 16);
            } else {
                pk[j] = (u0 >> 16) | u1;
            }
        }
        *(uint4*)&wepk[(size_t)idx * 8] = make_uint4(pk[0], pk[1], pk[2], pk[3]);
    } else if (bk < 96) {
        const int b = bk - 64;
        const int a = tid;
        dh_lds[a] = dh[b * E_ + a];
        __syncthreads();
        float acc = bias[a];
        const float* wrow = W + (size_t)a * DE_;
        #pragma unroll
        for (int d = 0; d < E_; d += 4) {
            float4 w = *(const float4*)(wrow + d);
            acc += dh_lds[d] * w.x + dh_lds[d+1] * w.y
                 + dh_lds[d+2] * w.z + dh_lds[d+3] * w.w;
        }
        proj[b * A_ + a] = acc;
    } else {
        #pragma unroll
        for (int j = tid; j < B_ * E_; j += 256) out[j] = 0.f;
    }
}

// ---- Scores: TS=128 s-rows/block, wave = 128s x 64a, 96 MFMA/chunk/wave.
// Two-barrier K-loop (R4 structure): eo reg-prefetch issued after barrier 2,
// We staged via coalesced global_load_lds. eo LDS stride 130 units
// (130 % 8 == 2 -> b128 writes & reads conflict-free by bank arithmetic).
__global__ __launch_bounds__(256, 2) void scores_kernel(
    const float* __restrict__ eo, const unsigned short* __restrict__ wepk,
    const float* __restrict__ proj,
    float* __restrict__ scores, float* __restrict__ nsq)
{
    // pool: [0,32768) we_hl (2048 units); [32768,49408) eo_hl (1040 units)
    // eo unit = plane*520 + kg*130 + row (row 0..127)
    // epilogue overlay: red4 [64 cols][130] floats @0; npart @33280; qpart @35328
    __shared__ __align__(16) unsigned char pool[49408];
    unsigned short* we_hl = (unsigned short*)pool;
    unsigned short* eo_hl = (unsigned short*)(pool + 32768);

    const int tid = threadIdx.x;
    const int b   = blockIdx.x & (B_ - 1);
    const int s0  = (blockIdx.x >> 5) * 128;
    const int w   = tid >> 6, l = tid & 63;
    const int lq  = l >> 4,  lr = l & 15;

    // eo staging map: 4 lanes per row, lane covers one kg (8 floats, 32 B)
    const int erow = tid >> 2;          // rows erow and erow+64
    const int ekg  = tid & 3;
    const float* ebase = eo + (size_t)(s0 + erow) * (B_ * E_) + b * E_ + ekg * 8;

    f32x4 acc[8][4];
    #pragma unroll
    for (int i = 0; i < 8; ++i)
        #pragma unroll
        for (int j = 0; j < 4; ++j)
            acc[i][j] = (f32x4){0.f, 0.f, 0.f, 0.f};
    float nacc[2] = {0.f, 0.f};

    // prologue: prefetch chunk-0 eo into registers
    float4 ea0 = *(const float4*)(ebase);
    float4 ea1 = *(const float4*)(ebase + 4);
    float4 eb0 = *(const float4*)(ebase + (size_t)64 * (B_ * E_));
    float4 eb1 = *(const float4*)(ebase + (size_t)64 * (B_ * E_) + 4);

    for (int c = 0; c < 8; ++c) {
        __syncthreads();   // prev compute's ds_reads done; LDS reusable
        // ---- convert + ds_write eo chunk c (b128, conflict-free)
        #pragma unroll
        for (int it = 0; it < 2; ++it) {
            float4 v0 = it ? eb0 : ea0;
            float4 v1 = it ? eb1 : ea1;
            nacc[it] += v0.x*v0.x + v0.y*v0.y + v0.z*v0.z + v0.w*v0.w
                      + v1.x*v1.x + v1.y*v1.y + v1.z*v1.z + v1.w*v1.w;
            float xs[8] = {v0.x, v0.y, v0.z, v0.w, v1.x, v1.y, v1.z, v1.w};
            unsigned int hp[4], lp[4];
            #pragma unroll
            for (int j = 0; j < 4; ++j) {
                unsigned int u0 = __float_as_uint(xs[2*j])   & 0xFFFF0000u;
                unsigned int u1 = __float_as_uint(xs[2*j+1]) & 0xFFFF0000u;
                hp[j] = (u0 >> 16) | u1;
                lp[j] = (unsigned int)f2bf(xs[2*j]   - __uint_as_float(u0))
                      | ((unsigned int)f2bf(xs[2*j+1] - __uint_as_float(u1)) << 16);
            }
            const int u = ekg * 130 + it * 64 + erow;
            *(uint4*)&eo_hl[(size_t)u * 8]         = make_uint4(hp[0], hp[1], hp[2], hp[3]);
            *(uint4*)&eo_hl[(size_t)(520 + u) * 8] = make_uint4(lp[0], lp[1], lp[2], lp[3]);
        }
        // ---- stage We chunk c: coalesced async global->LDS
        const unsigned short* gsrc = wepk + (size_t)c * 2048 * 8;
        #pragma unroll
        for (int it = 0; it < 8; ++it) {
            const int u = it * 256 + tid;
            __builtin_amdgcn_global_load_lds(
                (const __attribute__((address_space(1))) void*)(gsrc + (size_t)u * 8),
                (__attribute__((address_space(3))) void*)&we_hl[(size_t)u * 8],
                16, 0, 0);
        }
        __syncthreads();   // drains We DMA + eo writes
        if (c < 7) {       // prefetch next eo AFTER the barrier: in flight through MFMAs
            ea0 = *(const float4*)(ebase + (c + 1) * 32);
            ea1 = *(const float4*)(ebase + (c + 1) * 32 + 4);
            eb0 = *(const float4*)(ebase + (size_t)64 * (B_ * E_) + (c + 1) * 32);
            eb1 = *(const float4*)(ebase + (size_t)64 * (B_ * E_) + (c + 1) * 32 + 4);
        }
        // ---- compute chunk c: 96 MFMA per wave
        short8 bh[4], bl[4];
        #pragma unroll
        for (int nt = 0; nt < 4; ++nt) {
            const int bunit = lq * 256 + w * 64 + nt * 16 + lr;
            bh[nt] = *(const short8*)&we_hl[(size_t)bunit * 8];
            bl[nt] = *(const short8*)&we_hl[(size_t)(1024 + bunit) * 8];
        }
        #pragma unroll
        for (int mt = 0; mt < 8; ++mt) {
            const int au = lq * 130 + mt * 16 + lr;
            short8 ah = *(const short8*)&eo_hl[(size_t)au * 8];
            short8 al = *(const short8*)&eo_hl[(size_t)(520 + au) * 8];
            #pragma unroll
            for (int nt = 0; nt < 4; ++nt) {
                acc[mt][nt] = __builtin_amdgcn_mfma_f32_16x16x32_bf16(ah, bh[nt], acc[mt][nt], 0, 0, 0);
                acc[mt][nt] = __builtin_amdgcn_mfma_f32_16x16x32_bf16(ah, bl[nt], acc[mt][nt], 0, 0, 0);
                acc[mt][nt] = __builtin_amdgcn_mfma_f32_16x16x32_bf16(al, bh[nt], acc[mt][nt], 0, 0, 0);
            }
        }
    }
    __syncthreads();   // all fragment reads done before LDS overlay

    // ---- epilogue: tanh + reduce over a
    float* red4  = (float*)pool;                 // [64 cols][130] floats
    float* npart = (float*)(pool + 33280);       // 512 floats
    float* qpart = (float*)(pool + 35328);       // 256 floats
    float pr[4];
    #pragma unroll
    for (int nt = 0; nt < 4; ++nt) pr[nt] = proj[b * A_ + w * 64 + nt * 16 + lr];
    #pragma unroll
    for (int mt = 0; mt < 8; ++mt) {
        #pragma unroll
        for (int r = 0; r < 4; ++r) {
            float s = 0.f;
            #pragma unroll
            for (int nt = 0; nt < 4; ++nt)
                s += tanh_fast(pr[nt] + acc[mt][nt][r]);
            // C/D layout: col = lr (a-dim), row = mt*16 + lq*4 + r (s-dim)
            red4[(w * 16 + lr) * 130 + (mt * 16 + lq * 4 + r)] = s;
        }
    }
    npart[tid]       = nacc[0];   // partial of row tid>>2
    npart[256 + tid] = nacc[1];   // partial of row 64 + (tid>>2)
    __syncthreads();
    {   // 256 threads: (row = tid>>1, half = tid&1) sums 32 of 64 columns
        const int row = tid >> 1, half = tid & 1;
        float s = 0.f;
        #pragma unroll
        for (int j = 0; j < 32; ++j) s += red4[(half * 32 + j) * 130 + row];
        qpart[half * 128 + row] = s;
    }
    __syncthreads();
    if (tid < 128) {
        scores[b * S_ + s0 + tid] = qpart[tid] + qpart[128 + tid];
        const int base = (tid < 64) ? 4 * tid : 256 + 4 * (tid - 64);
        nsq[b * S_ + s0 + tid] = npart[base] + npart[base + 1]
                               + npart[base + 2] + npart[base + 3];
    }
}

// ---- Attend (softmax fused): per-b softmax stats recomputed per block from
// L2-hot scores, then 128-row partial of attended + attn_map rows.
__global__ __launch_bounds__(256) void attend_kernel(
    const float* __restrict__ eo, const float* __restrict__ scores,
    const float* __restrict__ nsq, float* __restrict__ out)
{
    __shared__ float red[256];
    __shared__ float4 acc_red[4][64];
    const int tid = threadIdx.x;
    const int b   = blockIdx.x & (B_ - 1);
    const int ch  = blockIdx.x / B_;

    float v[16];
    float m = -1e30f;
    #pragma unroll
    for (int i = 0; i < 16; ++i) {
        v[i] = scores[b * S_ + i * 256 + tid];
        m = fmaxf(m, v[i]);
    }
    red[tid] = m;
    __syncthreads();
    for (int off = 128; off > 0; off >>= 1) {
        if (tid < off) red[tid] = fmaxf(red[tid], red[tid + off]);
        __syncthreads();
    }
    m = red[0];
    __syncthreads();
    float sum = 0.f;
    #pragma unroll
    for (int i = 0; i < 16; ++i) sum += __expf(v[i] - m);
    red[tid] = sum;
    __syncthreads();
    for (int off = 128; off > 0; off >>= 1) {
        if (tid < off) red[tid] += red[tid + off];
        __syncthreads();
    }
    const float inv = 1.f / red[0];

    const int le = tid & 63, sg = tid >> 6;
    const int s0 = ch * 128 + sg * 32;
    float4 a = make_float4(0.f, 0.f, 0.f, 0.f);
    #pragma unroll 8
    for (int s = 0; s < 32; ++s) {
        float pv = __expf(scores[b * S_ + s0 + s] - m) * inv;
        float4 e = *(const float4*)(eo + (size_t)(s0 + s) * (B_ * E_)
                                       + b * E_ + le * 4);
        a.x = fmaf(pv, e.x, a.x);
        a.y = fmaf(pv, e.y, a.y);
        a.z = fmaf(pv, e.z, a.z);
        a.w = fmaf(pv, e.w, a.w);
    }
    acc_red[sg][le] = a;
    if (tid < 128) {
        const int s = ch * 128 + tid;
        float pv = __expf(scores[b * S_ + s] - m) * inv;
        out[B_ * E_ + b * S_ + s] = pv * sqrtf(nsq[b * S_ + s]);
    }
    __syncthreads();
    if (tid < 64) {
        float4 a0 = acc_red[0][tid], a1 = acc_red[1][tid];
        float4 a2 = acc_red[2][tid], a3 = acc_red[3][tid];
        float* dst = out + b * E_ + tid * 4;
        atomicAdd(dst + 0, a0.x + a1.x + a2.x + a3.x);
        atomicAdd(dst + 1, a0.y + a1.y + a2.y + a3.y);
        atomicAdd(dst + 2, a0.z + a1.z + a2.z + a3.z);
        atomicAdd(dst + 3, a0.w + a1.w + a2.w + a3.w);
    }
}

extern "C" void kernel_launch(void* const* d_in, const int* in_sizes, int n_in,
                              void* d_out, int out_size, void* d_ws, size_t ws_size,
                              hipStream_t stream)
{
    const float* dh   = (const float*)d_in[0];  // (1,B,D)
    const float* eo   = (const float*)d_in[1];  // (S,B,E)
    const float* W    = (const float*)d_in[2];  // (A, D+E)
    const float* bias = (const float*)d_in[3];  // (A,)
    float* out = (float*)d_out;                 // [attended 8192 | attn_map 131072]
    float* ws  = (float*)d_ws;

    float* projb  = ws;                           // 8192 floats
    float* nsqb   = ws + 8192;                    // 131072 floats
    float* scores = nsqb + S_ * B_;               // 131072 floats
    unsigned short* wepk = (unsigned short*)(scores + S_ * B_);  // 256 KB packed We

    prep_kernel   <<<97,              256, 0, stream>>>(W, dh, bias, wepk, projb, out);
    scores_kernel <<<B_ * (S_ / 128), 256, 0, stream>>>(eo, wepk, projb, scores, nsqb);
    attend_kernel <<<B_ * (S_ / 128), 256, 0, stream>>>(eo, scores, nsqb, out);
}